// Round 12
// baseline (307.222 us; speedup 1.0000x reference)
//
#include <hip/hip_runtime.h>
#include <stdint.h>

#define N_NODES 50000
#define N_EDGES 800000
#define HID 128
#define NWG_E (N_EDGES / 128)      // 6250 edge blocks
#define XQ (NWG_E / 8)             // 781
#define XR (NWG_E % 8)             // 2
#define SCAN_B 196                 // 196*256 = 50176 >= N_NODES
#define NX (N_NODES * 64)          // x elements

#define ENC_NEG_INF 0x007FFFFFu   // enc(-inf)

typedef short short8 __attribute__((ext_vector_type(8)));
typedef float f32x4 __attribute__((ext_vector_type(4)));

__device__ __forceinline__ unsigned enc_f32(float f) {
    unsigned u = __float_as_uint(f);
    return (u & 0x80000000u) ? ~u : (u | 0x80000000u);
}
__device__ __forceinline__ float dec_f32(unsigned e) {
    unsigned u = (e & 0x80000000u) ? (e & 0x7FFFFFFFu) : ~e;
    return __uint_as_float(u);
}
__device__ __forceinline__ unsigned short f2bf(float f) {
    unsigned u = __float_as_uint(f);
    unsigned r = (u + 0x7fffu + ((u >> 16) & 1u)) >> 16;
    return (unsigned short)r;
}
__device__ __forceinline__ float bf2f(unsigned short h) {
    return __uint_as_float(((unsigned)h) << 16);
}
__device__ __forceinline__ float wcat_val(const float* __restrict__ W, int K, int k, int n) {
    return (n < 128) ? (W[k * 128 + n] - W[(k + K) * 128 + n]) : W[(k + K) * 128 + (n - 128)];
}

// ---------------- fused setup: W-frag preps + x->bf16 + big fills ----------------
__global__ __launch_bounds__(256) void setup(
        const float* __restrict__ x,
        const float* __restrict__ W1a, const float* __restrict__ W1b,
        const float* __restrict__ W2a, const float* __restrict__ W2b,
        unsigned short* __restrict__ Xb,
        unsigned short* __restrict__ Wg1A,
        unsigned short* __restrict__ Wg1, unsigned short* __restrict__ Wg2,
        unsigned short* __restrict__ WCg2,
        unsigned* __restrict__ AGG1, unsigned* __restrict__ OUT,
        unsigned* __restrict__ count) {
    int bid = blockIdx.x, tid = threadIdx.x;
    const int NH = N_NODES * HID;

    if (bid < 128) {
        // Wg1/Wg2: Wb[128][128] -> hi-plane frags, HALF-MAJOR tile order
        const float* Wb = (bid < 64) ? W1b : W2b;
        unsigned short* Wg = (bid < 64) ? Wg1 : Wg2;
        int idx = (bid & 63) * 256 + tid;          // 0..16383
        int j = idx & 7, l = (idx >> 3) & 63, t = idx >> 9;
        int h = t >> 4, kt = (t >> 2) & 3, ntl = t & 3;
        int nt = 4 * h + ntl;
        int k = 32 * kt + 8 * (l >> 4) + j;
        int n = 16 * nt + (l & 15);
        Wg[idx] = f2bf(Wb[k * 128 + n]);
    } else if (bid < 192) {
        // Wg1A: W1a[128][128] -> hi-plane frags, half-major
        int idx = (bid - 128) * 256 + tid;
        int j = idx & 7, l = (idx >> 3) & 63, t = idx >> 9;
        int h = t >> 4, kt = (t >> 2) & 3, ntl = t & 3;
        int nt = 4 * h + ntl;
        int k = 32 * kt + 8 * (l >> 4) + j;
        int n = 16 * nt + (l & 15);
        Wg1A[idx] = f2bf(W1a[k * 128 + n]);
    } else if (bid < 320) {
        // WCg2: K=128, idx 0..32767, hi plane only
        int idx = (bid - 192) * 256 + tid;
        int j = idx & 7, l = (idx >> 3) & 63, nt = (idx >> 9) & 15, kt = idx >> 13;
        int k = 32 * kt + 8 * (l >> 4) + j;
        int n = 16 * nt + (l & 15);
        WCg2[idx] = f2bf(wcat_val(W2a, 128, k, n));
    }

    // fills: AGG1, OUT, count, Xb
    int total = 2 * NH + N_NODES + NX;
    for (int i = bid * 256 + tid; i < total; i += gridDim.x * 256) {
        if (i < NH) AGG1[i] = ENC_NEG_INF;
        else if (i < 2 * NH) OUT[i - NH] = ENC_NEG_INF;
        else if (i < 2 * NH + N_NODES) count[i - 2 * NH] = 0u;
        else Xb[i - 2 * NH - N_NODES] = f2bf(x[i - 2 * NH - N_NODES]);
    }
}

// final: encoded u32 -> decoded float + bias; empty segment -> 0
__global__ void out_decode(unsigned* __restrict__ p, const float* __restrict__ bias, int n) {
    int i = blockIdx.x * blockDim.x + threadIdx.x;
    int stride = gridDim.x * blockDim.x;
    for (; i < n; i += stride) {
        unsigned e = p[i];
        float f = (e == ENC_NEG_INF) ? 0.0f : dec_f32(e) + bias[i & 127];
        ((float*)p)[i] = f;
    }
}

// ---------------- sort-by-dst (counting sort, multi-block scan) ----------------

__global__ void hist_dst(const int* __restrict__ dst, unsigned* __restrict__ count) {
    int i = blockIdx.x * blockDim.x + threadIdx.x;
    if (i < N_EDGES) atomicAdd(&count[dst[i]], 1u);
}

__global__ __launch_bounds__(256) void scan_p1(const unsigned* __restrict__ count,
                                               unsigned* __restrict__ bsum) {
    __shared__ unsigned s[256];
    int t = threadIdx.x;
    int i = blockIdx.x * 256 + t;
    s[t] = (i < N_NODES) ? count[i] : 0u;
    __syncthreads();
    for (int off = 128; off > 0; off >>= 1) {
        if (t < off) s[t] += s[t + off];
        __syncthreads();
    }
    if (t == 0) bsum[blockIdx.x] = s[0];
}

__global__ __launch_bounds__(256) void scan_p2(unsigned* __restrict__ bsum) {
    __shared__ unsigned s[256];
    int t = threadIdx.x;
    unsigned v = (t < SCAN_B) ? bsum[t] : 0u;
    s[t] = v;
    __syncthreads();
    for (int off = 1; off < 256; off <<= 1) {
        unsigned x = (t >= off) ? s[t - off] : 0u;
        __syncthreads();
        s[t] += x;
        __syncthreads();
    }
    if (t < SCAN_B) bsum[t] = s[t] - v;   // exclusive
}

__global__ __launch_bounds__(256) void scan_p3(const unsigned* __restrict__ count,
                                               const unsigned* __restrict__ bsum,
                                               unsigned* __restrict__ cursor) {
    __shared__ unsigned s[256];
    int t = threadIdx.x;
    int i = blockIdx.x * 256 + t;
    unsigned v = (i < N_NODES) ? count[i] : 0u;
    s[t] = v;
    __syncthreads();
    for (int off = 1; off < 256; off <<= 1) {
        unsigned x = (t >= off) ? s[t - off] : 0u;
        __syncthreads();
        s[t] += x;
        __syncthreads();
    }
    if (i < N_NODES) cursor[i] = bsum[blockIdx.x] + s[t] - v;
}

__global__ void scatter_edges(const int* __restrict__ src, const int* __restrict__ dst,
                              unsigned* __restrict__ cursor,
                              int* __restrict__ ssrc, int* __restrict__ sdst) {
    int i = blockIdx.x * blockDim.x + threadIdx.x;
    if (i < N_EDGES) {
        int d = dst[i];
        unsigned p = atomicAdd(&cursor[d], 1u);
        ssrc[p] = src[i];
        sdst[p] = d;
    }
}

// ---------------- MFMA node GEMM (layer 2 only): C = relu(dec(A)+b1b) @ WC2_hi ----------------
template<int DEC, int KT>
__global__ __launch_bounds__(256, 3) void gemm_uv_mfma(
        const void* __restrict__ A_,
        const unsigned short* __restrict__ Wg,
        const float* __restrict__ bprev,
        const float* __restrict__ bu,
        unsigned short* __restrict__ C,
        int M) {
    __shared__ char lds[KT * 8192];
    const int K = 32 * KT;
    int tid = threadIdx.x;
    int bx = blockIdx.x, by = blockIdx.y;
    int r0 = bx * 128;
    int w = tid >> 6, l = tid & 63;
    int q = l >> 4, m = l & 15;

    short8 ahi[2][KT];
#pragma unroll
    for (int mt = 0; mt < 2; ++mt) {
        int row = r0 + 32 * w + 16 * mt + m;
        bool ok = row < M;
#pragma unroll
        for (int kt = 0; kt < KT; ++kt) {
            float av[8] = {0.f, 0.f, 0.f, 0.f, 0.f, 0.f, 0.f, 0.f};
            if (ok) {
                if (DEC) {
                    const unsigned* Ar = (const unsigned*)A_ + (size_t)row * K + 32 * kt + 8 * q;
                    uint4 x0 = *(const uint4*)Ar;
                    uint4 x1 = *(const uint4*)(Ar + 4);
                    float4 g0 = *(const float4*)&bprev[32 * kt + 8 * q];
                    float4 g1 = *(const float4*)&bprev[32 * kt + 8 * q + 4];
                    av[0] = fmaxf(dec_f32(x0.x) + g0.x, 0.f);
                    av[1] = fmaxf(dec_f32(x0.y) + g0.y, 0.f);
                    av[2] = fmaxf(dec_f32(x0.z) + g0.z, 0.f);
                    av[3] = fmaxf(dec_f32(x0.w) + g0.w, 0.f);
                    av[4] = fmaxf(dec_f32(x1.x) + g1.x, 0.f);
                    av[5] = fmaxf(dec_f32(x1.y) + g1.y, 0.f);
                    av[6] = fmaxf(dec_f32(x1.z) + g1.z, 0.f);
                    av[7] = fmaxf(dec_f32(x1.w) + g1.w, 0.f);
                } else {
                    const float* Ar = (const float*)A_ + (size_t)row * K + 32 * kt + 8 * q;
                    float4 f0 = *(const float4*)Ar;
                    float4 f1 = *(const float4*)(Ar + 4);
                    av[0] = f0.x; av[1] = f0.y; av[2] = f0.z; av[3] = f0.w;
                    av[4] = f1.x; av[5] = f1.y; av[6] = f1.z; av[7] = f1.w;
                }
            }
            short8 hi;
#pragma unroll
            for (int j = 0; j < 8; ++j) hi[j] = (short)f2bf(av[j]);
            ahi[mt][kt] = hi;
        }
    }

    f32x4 acc[2][8];
#pragma unroll
    for (int mt = 0; mt < 2; ++mt)
#pragma unroll
        for (int nt = 0; nt < 8; ++nt)
            acc[mt][nt] = (f32x4){0.f, 0.f, 0.f, 0.f};

    const short8* bfr = (const short8*)lds;

    {
        const float4* s4 = (const float4*)Wg;
        float4* d4 = (float4*)lds;
#pragma unroll
        for (int it = 0; it < 2 * KT; ++it) {
            int f = 256 * it + tid;
            int tl = f >> 6, fin = f & 63;
            int tg = (tl >> 3) * 16 + 8 * by + (tl & 7);
            d4[f] = s4[tg * 64 + fin];
        }
    }
    __syncthreads();
#pragma unroll
    for (int nt = 0; nt < 8; ++nt)
#pragma unroll
        for (int kt = 0; kt < KT; ++kt) {
            short8 b = bfr[(kt * 8 + nt) * 64 + l];
            acc[0][nt] = __builtin_amdgcn_mfma_f32_16x16x32_bf16(ahi[0][kt], b, acc[0][nt], 0, 0, 0);
            acc[1][nt] = __builtin_amdgcn_mfma_f32_16x16x32_bf16(ahi[1][kt], b, acc[1][nt], 0, 0, 0);
        }

#pragma unroll
    for (int nt = 0; nt < 8; ++nt) {
        float bias = (by == 0) ? bu[16 * nt + m] : 0.f;
#pragma unroll
        for (int mt = 0; mt < 2; ++mt) {
            int rowb = r0 + 32 * w + 16 * mt + 4 * q;
#pragma unroll
            for (int r = 0; r < 4; ++r) {
                int row = rowb + r;
                if (row < M)
                    C[(size_t)row * 256 + 128 * by + 16 * nt + m] = f2bf(acc[mt][nt][r] + bias);
            }
        }
    }
}

// ---------------- layer-1 fused edge kernel ----------------
// Gather x~[d], x~[s] (64-dim bf16, 128 B rows); A = [x~d || x~s - x~d] (K=128);
// P = A @ W1a; T = relu(P + b1a) -> swizzled LDS tile (wave-private rows);
// M = T @ W1b; segmented max -> AGG1. W stages in 16KB halves.
__global__ __launch_bounds__(256, 3) void edge_conv1(
        const unsigned short* __restrict__ Xb,   // [N][64] bf16
        const unsigned short* __restrict__ WgA,  // W1a frags, half-major (16384 shorts)
        const unsigned short* __restrict__ WgB,  // W1b frags, half-major (16384 shorts)
        const float* __restrict__ ba,            // b1a [128]
        const int* __restrict__ ssrc,
        const int* __restrict__ sdst,
        unsigned* __restrict__ AGG) {
    __shared__ char lds[49152];   // [0,16K) Wbuf | [16K,48K) T tile 128x256B (XOR swz)
    int tid = threadIdx.x;
    int orig = blockIdx.x;
    int xcd = orig & 7, ii = orig >> 3;
    int wg = (xcd < XR) ? xcd * (XQ + 1) + ii : XR * (XQ + 1) + (xcd - XR) * XQ + ii;
    int e0 = wg * 128;
    int w = tid >> 6, l = tid & 63;
    int q = l >> 4, m = l & 15;

    // gather x rows (all loads issued up front)
    int eA = e0 + 32 * w + m;
    int d0 = sdst[eA], s0 = ssrc[eA];
    int d1 = sdst[eA + 16], s1 = ssrc[eA + 16];
    const short8* Xd0 = (const short8*)&Xb[(size_t)d0 * 64];
    const short8* Xs0 = (const short8*)&Xb[(size_t)s0 * 64];
    const short8* Xd1 = (const short8*)&Xb[(size_t)d1 * 64];
    const short8* Xs1 = (const short8*)&Xb[(size_t)s1 * 64];
    short8 xd0a = Xd0[q], xd0b = Xd0[4 + q];
    short8 xs0a = Xs0[q], xs0b = Xs0[4 + q];
    short8 xd1a = Xd1[q], xd1b = Xd1[4 + q];
    short8 xs1a = Xs1[q], xs1b = Xs1[4 + q];

    // seg-max window dsts (register-resident)
    int4 dw[4];
    {
        const int4* dsrc = (const int4*)&sdst[e0 + 32 * w + 16 * (l >> 5)];
        dw[0] = dsrc[0]; dw[1] = dsrc[1]; dw[2] = dsrc[2]; dw[3] = dsrc[3];
    }

    // stage W1a half 0
    float4* d4 = (float4*)lds;
    {
        const float4* s4 = (const float4*)WgA;
#pragma unroll
        for (int i = 0; i < 4; ++i) d4[tid + 256 * i] = s4[tid + 256 * i];
    }

    // A frags: kt0/1 = x~d (copy), kt2/3 = bf16(x~s - x~d)
    short8 a0[4], a1[4];
    a0[0] = xd0a; a0[1] = xd0b;
    a1[0] = xd1a; a1[1] = xd1b;
#pragma unroll
    for (int j = 0; j < 8; ++j) {
        a0[2][j] = (short)f2bf(bf2f((unsigned short)xs0a[j]) - bf2f((unsigned short)xd0a[j]));
        a0[3][j] = (short)f2bf(bf2f((unsigned short)xs0b[j]) - bf2f((unsigned short)xd0b[j]));
        a1[2][j] = (short)f2bf(bf2f((unsigned short)xs1a[j]) - bf2f((unsigned short)xd1a[j]));
        a1[3][j] = (short)f2bf(bf2f((unsigned short)xs1b[j]) - bf2f((unsigned short)xd1b[j]));
    }

    const short8* bfr = (const short8*)lds;
    char* Tb = lds + 16384;
    f32x4 p0[4], p1[4];

    __syncthreads();   // b1: W1a h0 ready

    // ---- GEMM1 h0 ----
#pragma unroll
    for (int ntl = 0; ntl < 4; ++ntl) { p0[ntl] = (f32x4){0,0,0,0}; p1[ntl] = (f32x4){0,0,0,0}; }
#pragma unroll
    for (int ntl = 0; ntl < 4; ++ntl)
#pragma unroll
        for (int kt = 0; kt < 4; ++kt) {
            short8 b = bfr[(kt * 4 + ntl) * 64 + l];
            p0[ntl] = __builtin_amdgcn_mfma_f32_16x16x32_bf16(a0[kt], b, p0[ntl], 0, 0, 0);
            p1[ntl] = __builtin_amdgcn_mfma_f32_16x16x32_bf16(a1[kt], b, p1[ntl], 0, 0, 0);
        }
    __syncthreads();   // b2: h0 readers done

    // stage W1a h1 + write T h0 (T is wave-private rows; no barrier needed for T)
    {
        const float4* s4 = (const float4*)WgA + 1024;
#pragma unroll
        for (int i = 0; i < 4; ++i) d4[tid + 256 * i] = s4[tid + 256 * i];
    }
#pragma unroll
    for (int ntl = 0; ntl < 4; ++ntl) {
        int colg = 16 * ntl + m;   // h=0
        float bav = ba[colg];
#pragma unroll
        for (int mt = 0; mt < 2; ++mt)
#pragma unroll
            for (int r = 0; r < 4; ++r) {
                int E = 32 * w + 16 * mt + 4 * q + r;
                float v = fmaxf((mt ? p1[ntl][r] : p0[ntl][r]) + bav, 0.f);
                unsigned boff = ((unsigned)(E << 8) + (colg << 1)) ^ ((unsigned)(E & 7) << 4);
                *(short*)(Tb + boff) = (short)f2bf(v);
            }
    }
    __syncthreads();   // b3: W1a h1 ready

    // ---- GEMM1 h1 ----
#pragma unroll
    for (int ntl = 0; ntl < 4; ++ntl) { p0[ntl] = (f32x4){0,0,0,0}; p1[ntl] = (f32x4){0,0,0,0}; }
#pragma unroll
    for (int ntl = 0; ntl < 4; ++ntl)
#pragma unroll
        for (int kt = 0; kt < 4; ++kt) {
            short8 b = bfr[(kt * 4 + ntl) * 64 + l];
            p0[ntl] = __builtin_amdgcn_mfma_f32_16x16x32_bf16(a0[kt], b, p0[ntl], 0, 0, 0);
            p1[ntl] = __builtin_amdgcn_mfma_f32_16x16x32_bf16(a1[kt], b, p1[ntl], 0, 0, 0);
        }
    __syncthreads();   // b4: h1 readers done

    // stage W1b h0 + write T h1 + read A2 frags from T (own rows, lgkm-ordered)
    {
        const float4* s4 = (const float4*)WgB;
#pragma unroll
        for (int i = 0; i < 4; ++i) d4[tid + 256 * i] = s4[tid + 256 * i];
    }
#pragma unroll
    for (int ntl = 0; ntl < 4; ++ntl) {
        int colg = 64 + 16 * ntl + m;   // h=1
        float bav = ba[colg];
#pragma unroll
        for (int mt = 0; mt < 2; ++mt)
#pragma unroll
            for (int r = 0; r < 4; ++r) {
                int E = 32 * w + 16 * mt + 4 * q + r;
                float v = fmaxf((mt ? p1[ntl][r] : p0[ntl][r]) + bav, 0.f);
                unsigned boff = ((unsigned)(E << 8) + (colg << 1)) ^ ((unsigned)(E & 7) << 4);
                *(short*)(Tb + boff) = (short)f2bf(v);
            }
    }
    short8 a2[2][4];
#pragma unroll
    for (int mt = 0; mt < 2; ++mt)
#pragma unroll
        for (int kt = 0; kt < 4; ++kt) {
            int E = 32 * w + 16 * mt + m;
            unsigned roff = ((unsigned)(E << 8) + (kt << 6) + (q << 4)) ^ ((unsigned)(m & 7) << 4);
            a2[mt][kt] = *(const short8*)(Tb + roff);
        }
    __syncthreads();   // b5: W1b h0 ready

    // ---- GEMM2 h0 ----
    f32x4 qa[2][4];
#pragma unroll
    for (int mt = 0; mt < 2; ++mt)
#pragma unroll
        for (int ntl = 0; ntl < 4; ++ntl) qa[mt][ntl] = (f32x4){0,0,0,0};
#pragma unroll
    for (int ntl = 0; ntl < 4; ++ntl)
#pragma unroll
        for (int kt = 0; kt < 4; ++kt) {
            short8 b = bfr[(kt * 4 + ntl) * 64 + l];
            qa[0][ntl] = __builtin_amdgcn_mfma_f32_16x16x32_bf16(a2[0][kt], b, qa[0][ntl], 0, 0, 0);
            qa[1][ntl] = __builtin_amdgcn_mfma_f32_16x16x32_bf16(a2[1][kt], b, qa[1][ntl], 0, 0, 0);
        }
    __syncthreads();   // b6: readers done
    {
        const float4* s4 = (const float4*)WgB + 1024;
#pragma unroll
        for (int i = 0; i < 4; ++i) d4[tid + 256 * i] = s4[tid + 256 * i];
    }
    __syncthreads();   // b7: W1b h1 ready

    // ---- GEMM2 h1 ----
    f32x4 qb[2][4];
#pragma unroll
    for (int mt = 0; mt < 2; ++mt)
#pragma unroll
        for (int ntl = 0; ntl < 4; ++ntl) qb[mt][ntl] = (f32x4){0,0,0,0};
#pragma unroll
    for (int ntl = 0; ntl < 4; ++ntl)
#pragma unroll
        for (int kt = 0; kt < 4; ++kt) {
            short8 b = bfr[(kt * 4 + ntl) * 64 + l];
            qb[0][ntl] = __builtin_amdgcn_mfma_f32_16x16x32_bf16(a2[0][kt], b, qb[0][ntl], 0, 0, 0);
            qb[1][ntl] = __builtin_amdgcn_mfma_f32_16x16x32_bf16(a2[1][kt], b, qb[1][ntl], 0, 0, 0);
        }

    // ---- reduce both halves (M2 in T region; all T reads completed pre-b7) ----
    float* M2 = (float*)(lds + 16384 + w * 4224);   // wave-private [32][33] f32
    const int* dwp = (const int*)dw;
#pragma unroll
    for (int h = 0; h < 2; ++h) {
#pragma unroll
        for (int cn = 0; cn < 2; ++cn) {
#pragma unroll
            for (int nt2 = 0; nt2 < 2; ++nt2) {
                int ntl = 2 * cn + nt2;
#pragma unroll
                for (int mt = 0; mt < 2; ++mt)
#pragma unroll
                    for (int r = 0; r < 4; ++r) {
                        float v = h ? qb[mt][ntl][r] : qa[mt][ntl][r];
                        M2[(16 * mt + 4 * q + r) * 33 + 16 * nt2 + m] = v;
                    }
            }
            {
                int c = l & 31;
                int cur = dwp[0];
                float mx = -3.402823466e38f;
#pragma unroll
                for (int i = 0; i < 16; ++i) {
                    int de = dwp[i];
                    if (de != cur) {
                        atomicMax(&AGG[(size_t)cur * 128 + 64 * h + 32 * cn + c], enc_f32(mx));
                        cur = de;
                        mx = -3.402823466e38f;
                    }
                    mx = fmaxf(mx, M2[(16 * (l >> 5) + i) * 33 + c]);
                }
                atomicMax(&AGG[(size_t)cur * 128 + 64 * h + 32 * cn + c], enc_f32(mx));
            }
        }
    }
}

// ---------------- MFMA edge MLP layer 2 (unchanged from R10) ----------------
__global__ __launch_bounds__(256, 4) void edge_mlp_mfma(
        const unsigned short* __restrict__ UV,
        const unsigned short* __restrict__ Wg,
        const int* __restrict__ ssrc,
        const int* __restrict__ sdst,
        unsigned* __restrict__ AGG) {
    __shared__ char lds[16384 + 4 * 4352];
    int tid = threadIdx.x;
    int orig = blockIdx.x;
    int xcd = orig & 7, ii = orig >> 3;
    int wg = (xcd < XR) ? xcd * (XQ + 1) + ii : XR * (XQ + 1) + (xcd - XR) * XQ + ii;
    int e0 = wg * 128;
    int w = tid >> 6, l = tid & 63;
    int q = l >> 4, m = l & 15;

    short8 ub[2][4], vb[2][4];
    {
        int eA = e0 + 32 * w + m;
        int d0 = sdst[eA], s0 = ssrc[eA];
        int d1 = sdst[eA + 16], s1 = ssrc[eA + 16];
        const short8* Ud0 = (const short8*)&UV[(size_t)d0 * 256];
        const short8* Vs0 = (const short8*)&UV[(size_t)s0 * 256 + 128];
        const short8* Ud1 = (const short8*)&UV[(size_t)d1 * 256];
        const short8* Vs1 = (const short8*)&UV[(size_t)s1 * 256 + 128];
#pragma unroll
        for (int kt = 0; kt < 4; ++kt) {
            ub[0][kt] = Ud0[4 * kt + q];
            vb[0][kt] = Vs0[4 * kt + q];
            ub[1][kt] = Ud1[4 * kt + q];
            vb[1][kt] = Vs1[4 * kt + q];
        }
    }

    int4 dw[4];
    {
        const int4* dsrc = (const int4*)&sdst[e0 + 32 * w + 16 * (l >> 5)];
        dw[0] = dsrc[0]; dw[1] = dsrc[1]; dw[2] = dsrc[2]; dw[3] = dsrc[3];
    }

    {
        const float4* s4 = (const float4*)Wg;
        float4* d4 = (float4*)lds;
#pragma unroll
        for (int i = 0; i < 4; ++i) d4[tid + 256 * i] = s4[tid + 256 * i];
    }

    short8 ahi[2][4];
#pragma unroll
    for (int mt = 0; mt < 2; ++mt)
#pragma unroll
        for (int kt = 0; kt < 4; ++kt) {
            short8 hi;
#pragma unroll
            for (int j = 0; j < 8; ++j) {
                float t = bf2f((unsigned short)ub[mt][kt][j]) + bf2f((unsigned short)vb[mt][kt][j]);
                hi[j] = (short)f2bf(fmaxf(t, 0.f));
            }
            ahi[mt][kt] = hi;
        }

    __syncthreads();

    const short8* bfr = (const short8*)lds;
    float* M2 = (float*)(lds + 16384 + w * 4352);
    f32x4 acc[2][4];

#pragma unroll
    for (int h = 0; h < 2; ++h) {
#pragma unroll
        for (int mt = 0; mt < 2; ++mt)
#pragma unroll
            for (int ntl = 0; ntl < 4; ++ntl)
                acc[mt][ntl] = (f32x4){0.f, 0.f, 0.f, 0.f};
#pragma unroll
        for (int ntl = 0; ntl < 4; ++ntl)
#pragma unroll
            for (int kt = 0; kt < 4; ++kt) {
                short8 b = bfr[(kt * 4 + ntl) * 64 + l];
                acc[0][ntl] = __builtin_amdgcn_mfma_f32_16x16x32_bf16(ahi[0][kt], b, acc[0][ntl], 0, 0, 0);
                acc[1][ntl] = __builtin_amdgcn_mfma_f32_16x16x32_bf16(ahi[1][kt], b, acc[1][ntl], 0, 0, 0);
            }

        if (h == 0) {
            __syncthreads();
            const float4* s4 = (const float4*)Wg + 1024;
            float4* d4 = (float4*)lds;
#pragma unroll
            for (int i = 0; i < 4; ++i) d4[tid + 256 * i] = s4[tid + 256 * i];
        }

#pragma unroll
        for (int cn = 0; cn < 2; ++cn) {
#pragma unroll
            for (int nt2 = 0; nt2 < 2; ++nt2) {
                int ntl = 2 * cn + nt2;
#pragma unroll
                for (int mt = 0; mt < 2; ++mt)
#pragma unroll
                    for (int r = 0; r < 4; ++r)
                        M2[(16 * mt + 4 * q + r) * 34 + 16 * nt2 + m] = acc[mt][ntl][r];
            }
            {
                int c = l & 31;
                const int* dwp = (const int*)dw;
                int cur = dwp[0];
                float mx = -3.402823466e38f;
#pragma unroll
                for (int i = 0; i < 16; ++i) {
                    int de = dwp[i];
                    if (de != cur) {
                        atomicMax(&AGG[(size_t)cur * 128 + 64 * h + 32 * cn + c], enc_f32(mx));
                        cur = de;
                        mx = -3.402823466e38f;
                    }
                    mx = fmaxf(mx, M2[(16 * (l >> 5) + i) * 34 + c]);
                }
                atomicMax(&AGG[(size_t)cur * 128 + 64 * h + 32 * cn + c], enc_f32(mx));
            }
        }

        if (h == 0) __syncthreads();
    }
}

// ---------------- launch ----------------

extern "C" void kernel_launch(void* const* d_in, const int* in_sizes, int n_in,
                              void* d_out, int out_size, void* d_ws, size_t ws_size,
                              hipStream_t stream) {
    const float* x   = (const float*)d_in[0];
    const int*   ei  = (const int*)d_in[1];
    const float* W1a = (const float*)d_in[2];
    const float* b1a = (const float*)d_in[3];
    const float* W1b = (const float*)d_in[4];
    const float* b1b = (const float*)d_in[5];
    const float* W2a = (const float*)d_in[6];
    const float* b2a = (const float*)d_in[7];
    const float* W2b = (const float*)d_in[8];
    const float* b2b = (const float*)d_in[9];
    const int* src = ei;
    const int* dst = ei + N_EDGES;

    char* ws = (char*)d_ws;
    unsigned short* UV    = (unsigned short*)ws;                 // 25.6 MB (bf16, layer 2)
    unsigned*       AGG1  = (unsigned*)(ws + 25600000);          // 25.6 MB
    int*            ssrc  = (int*)(ws + 51200000);               // 3.2 MB
    int*            sdst  = (int*)(ws + 54400000);               // 3.2 MB
    unsigned*       count = (unsigned*)(ws + 57600000);          // 200 KB
    unsigned*       cursor= (unsigned*)(ws + 57800000);          // 200 KB
    unsigned short* Wg1   = (unsigned short*)(ws + 58000000);    // 32 KB (W1b hi, half-major)
    unsigned short* Wg2   = (unsigned short*)(ws + 58065536);    // 32 KB (W2b hi)
    unsigned short* Wg1A  = (unsigned short*)(ws + 58131072);    // 32 KB (W1a hi)
    unsigned short* WCg2  = (unsigned short*)(ws + 58393216);    // 64 KB (WC2 hi)
    unsigned*       bsum  = (unsigned*)(ws + 58655744);          // 1 KB
    unsigned short* Xb    = (unsigned short*)(ws + 58656768);    // 6.4 MB (x bf16)

    const int NH = N_NODES * HID;   // 6.4M

    setup<<<2048, 256, 0, stream>>>(x, W1a, W1b, W2a, W2b, Xb, Wg1A, Wg1, Wg2, WCg2,
                                    AGG1, (unsigned*)d_out, count);

    // counting sort of edges by dst
    hist_dst<<<3125, 256, 0, stream>>>(dst, count);
    scan_p1<<<SCAN_B, 256, 0, stream>>>(count, bsum);
    scan_p2<<<1, 256, 0, stream>>>(bsum);
    scan_p3<<<SCAN_B, 256, 0, stream>>>(count, bsum, cursor);
    scatter_edges<<<3125, 256, 0, stream>>>(src, dst, cursor, ssrc, sdst);

    // Layer 1: fully fused (gathers x~ directly; no node GEMM)
    edge_conv1<<<NWG_E, 256, 0, stream>>>(Xb, Wg1A, Wg1, b1a, ssrc, sdst, AGG1);

    // Layer 2: node GEMM (relu+b1b fused) then edge MLP
    gemm_uv_mfma<1, 4><<<dim3(391, 2), 256, 0, stream>>>(AGG1, WCg2, b1b, b2a, UV, N_NODES);
    edge_mlp_mfma<<<NWG_E, 256, 0, stream>>>(UV, Wg2, ssrc, sdst, (unsigned*)d_out);
    out_decode<<<2048, 256, 0, stream>>>((unsigned*)d_out, b2b, NH);
}